// Round 4
// baseline (264.627 us; speedup 1.0000x reference)
//
#include <hip/hip_runtime.h>
#include <math.h>

#define CC 10    // classes
#define KK 50    // neighbors
#define RPB 16   // rows per block in kA
#define TPR 16   // threads per row in kA  (RPB*TPR == 256)
#define NBF (KK*CC)      // 500 floats per neighbor row
#define NBSTRIDE 501     // odd LDS stride -> only 2-way bank aliasing (free)

// ---- kA: stage 16 rows to LDS (coalesced), online-softmax attention beta,
//          fused wap/flag0/b_count/hist ------------------------------------
__global__ __launch_bounds__(256)
void kA(const float* __restrict__ aw, const float* __restrict__ an,
        const float* __restrict__ nbr, const float* __restrict__ att,
        const float* __restrict__ proj,
        float* __restrict__ wap, float* __restrict__ beta,
        int* __restrict__ flag0, int* __restrict__ scal,
        int* __restrict__ hist, int B)
{
  __shared__ float nb_lds[RPB * NBSTRIDE];   // 8016 floats
  __shared__ float an_lds[RPB * CC];         // 160 floats
  __shared__ float coef_lds[CC];             // 10 floats   (total ~32.7KB)

  int r0   = blockIdx.x * RPB;
  int nrow = B - r0; if (nrow > RPB) nrow = RPB;

  if (threadIdx.x < CC) {
    float d = proj[threadIdx.x * CC + threadIdx.x];
    coef_lds[threadIdx.x] = att[threadIdx.x] * d * d;
  }
  // stage anchors rows (contiguous nrow*10 floats)
  if (threadIdx.x < nrow * CC) {
    an_lds[threadIdx.x] = an[(size_t)r0 * CC + threadIdx.x];
  }
  // stage neighbor rows: nrow*500 floats contiguous, float4 coalesced
  {
    const float4* src = reinterpret_cast<const float4*>(nbr + (size_t)r0 * NBF);
    int nf4 = nrow * (NBF / 4);
    for (int f = threadIdx.x; f < nf4; f += 256) {
      float4 v = src[f];
      int fi  = f * 4;
      int r   = fi / NBF;
      int col = fi - r * NBF;
      float* dst = &nb_lds[r * NBSTRIDE + col];
      dst[0] = v.x; dst[1] = v.y; dst[2] = v.z; dst[3] = v.w;
    }
  }
  __syncthreads();

  int r = threadIdx.x >> 4;        // row within block
  int j = threadIdx.x & (TPR - 1); // lane within row
  if (r >= nrow) return;
  int row = r0 + r;

  float img[CC], ci[CC];
#pragma unroll
  for (int c = 0; c < CC; ++c) {
    img[c] = an_lds[r * CC + c];             // broadcast within row group
    ci[c]  = coef_lds[c] * img[c];
  }

  // online softmax-weighted q_hat over this lane's neighbors (k = j + 16t)
  float m = -INFINITY, den = 0.f;
  float qh[CC];
#pragma unroll
  for (int c = 0; c < CC; ++c) qh[c] = 0.f;

  for (int k = j; k < KK; k += TPR) {
    const float* nbp_ = &nb_lds[r * NBSTRIDE + k * CC];
    float nb[CC];
#pragma unroll
    for (int c = 0; c < CC; ++c) nb[c] = nbp_[c];

    float s = 0.f;
#pragma unroll
    for (int c = 0; c < CC; ++c) s = fmaf(ci[c], nb[c], s);
    s = (s > 0.f) ? s : 0.01f * s;           // leaky_relu

    float mx = nb[0];
#pragma unroll
    for (int c = 1; c < CC; ++c) mx = fmaxf(mx, nb[c]);
    float en[CC]; float sn = 0.f;
#pragma unroll
    for (int c = 0; c < CC; ++c) { en[c] = expf(nb[c] - mx); sn += en[c]; }

    if (s > m) {
      float corr = expf(m - s);              // expf(-inf)=0 on first iter
      den *= corr;
#pragma unroll
      for (int c = 0; c < CC; ++c) qh[c] *= corr;
      m = s;
    }
    float e   = expf(s - m);
    den += e;
    float esc = e / sn;
#pragma unroll
    for (int c = 0; c < CC; ++c) qh[c] = fmaf(esc, en[c], qh[c]);
  }

  // merge the 16 per-lane online states (4-step butterfly within row group)
#pragma unroll
  for (int off = 1; off <= 8; off <<= 1) {
    float mo   = __shfl_xor(m, off);
    float deno = __shfl_xor(den, off);
    float qho[CC];
#pragma unroll
    for (int c = 0; c < CC; ++c) qho[c] = __shfl_xor(qh[c], off);
    float mn = fmaxf(m, mo);
    float c1 = expf(m - mn), c2 = expf(mo - mn);
    den = den * c1 + deno * c2;
#pragma unroll
    for (int c = 0; c < CC; ++c) qh[c] = qh[c] * c1 + qho[c] * c2;
    m = mn;
  }

  if (j == 0) {
    // beta = || softmax(anchors) - q_hat ||^2
    float m2 = img[0];
#pragma unroll
    for (int c = 1; c < CC; ++c) m2 = fmaxf(m2, img[c]);
    float s2 = 0.f; float ap[CC];
#pragma unroll
    for (int c = 0; c < CC; ++c) { ap[c] = expf(img[c] - m2); s2 += ap[c]; }
    float inv2 = 1.f / s2, invd = 1.f / den;
    float bs = 0.f;
#pragma unroll
    for (int c = 0; c < CC; ++c) { float d = ap[c] * inv2 - qh[c] * invd; bs += d * d; }
    beta[row] = bs;

    // wap = softmax(anchors_weak), flag0, b_count, hist of beta hi-16
    float x[CC];
    const float2* p = reinterpret_cast<const float2*>(aw + (size_t)row * CC);
#pragma unroll
    for (int c = 0; c < CC / 2; ++c) { float2 t = p[c]; x[2*c] = t.x; x[2*c+1] = t.y; }
    float mw = x[0];
#pragma unroll
    for (int c = 1; c < CC; ++c) mw = fmaxf(mw, x[c]);
    float sw = 0.f;
#pragma unroll
    for (int c = 0; c < CC; ++c) { x[c] = expf(x[c] - mw); sw += x[c]; }
    float isw = 1.f / sw; float mp = 0.f;
#pragma unroll
    for (int c = 0; c < CC; ++c) { x[c] *= isw; mp = fmaxf(mp, x[c]); }
    float2* q = reinterpret_cast<float2*>(wap + (size_t)row * CC);
#pragma unroll
    for (int c = 0; c < CC / 2; ++c) { float2 t; t.x = x[2*c]; t.y = x[2*c+1]; q[c] = t; }
    int f = (mp > 0.15f) ? 1 : 0;
    flag0[row] = f;
    if (f) {
      atomicAdd(&scal[0], 1);
      unsigned key = __float_as_uint(bs);   // beta >= 0 -> order-preserving bits
      atomicAdd(&hist[key >> 16], 1);
    }
  }
}

// ---------------- K3: exact radix select of k-th smallest beta --------------
// scal: [0]=b_count [2]=sel_hi [3]=k2 [4]=k ; (float at [8]) = tau
__global__ __launch_bounds__(1024)
void k3b_sel(const int* __restrict__ hist, int* __restrict__ scal,
             int* __restrict__ hist2_zero)
{
  __shared__ int tmp[1024];
  int t = threadIdx.x;
  for (int jj = 0; jj < 64; ++jj) hist2_zero[t * 64 + jj] = 0;  // zero next pass
  int base = t * 64;
  int sum = 0;
  for (int jj = 0; jj < 64; ++jj) sum += hist[base + jj];
  tmp[t] = sum;
  __syncthreads();
  for (int off = 1; off < 1024; off <<= 1) {
    int v = (t >= off) ? tmp[t - off] : 0;
    __syncthreads();
    tmp[t] += v;
    __syncthreads();
  }
  int cumb = tmp[t] - sum;
  int b = scal[0];
  int k = (int)(0.5 * (double)b);   // int(ETA*b)
  if (k < 1) k = 1;
  if (t == 0) scal[4] = k;
  if (b > 0 && k > cumb && k <= cumb + sum) {
    int c = cumb;
    for (int jj = 0; jj < 64; ++jj) {
      int h = hist[base + jj];
      if (k <= c + h) { scal[2] = base + jj; scal[3] = k - c; break; }
      c += h;
    }
  }
  if (b == 0 && t == 0) { scal[2] = 0; scal[3] = 1; }
}

__global__ __launch_bounds__(256)
void k3c_hist2(const float* __restrict__ beta, const int* __restrict__ flag0,
               const int* __restrict__ scal, int* __restrict__ hist2, int B)
{
  int i = blockIdx.x * 256 + threadIdx.x;
  if (i >= B) return;
  if (flag0[i]) {
    unsigned key = __float_as_uint(beta[i]);
    if ((int)(key >> 16) == scal[2]) atomicAdd(&hist2[key & 0xFFFF], 1);
  }
}

__global__ __launch_bounds__(1024)
void k3d_tau(const int* __restrict__ hist2, int* __restrict__ scal,
             float* __restrict__ tau)
{
  __shared__ int tmp[1024];
  int t = threadIdx.x;
  int base = t * 64;
  int sum = 0;
  for (int jj = 0; jj < 64; ++jj) sum += hist2[base + jj];
  tmp[t] = sum;
  __syncthreads();
  for (int off = 1; off < 1024; off <<= 1) {
    int v = (t >= off) ? tmp[t - off] : 0;
    __syncthreads();
    tmp[t] += v;
    __syncthreads();
  }
  int cumb = tmp[t] - sum;
  int k2 = scal[3];
  if (k2 > cumb && k2 <= cumb + sum) {
    int c = cumb;
    for (int jj = 0; jj < 64; ++jj) {
      int h = hist2[base + jj];
      if (k2 <= c + h) {
        unsigned key = (((unsigned)scal[2]) << 16) | (unsigned)(base + jj);
        float bk = __uint_as_float(key);
        *tau = bk / expf(-1.0f);
        break;
      }
      c += h;
    }
  }
}

// ---------------- K4: q, target, mask1, per-block counts --------------------
__global__ __launch_bounds__(256)
void k4_q(const float* __restrict__ wap, const float* __restrict__ beta,
          const int* __restrict__ flag0, const float* __restrict__ tau_p,
          float* __restrict__ qbuf, int* __restrict__ target, int* __restrict__ flag1,
          int* __restrict__ counts, int* __restrict__ blockcnt, int B)
{
  __shared__ int lcnt[CC];
  if (threadIdx.x < CC) lcnt[threadIdx.x] = 0;
  __syncthreads();

  int i = blockIdx.x * 256 + threadIdx.x;
  int f = 0;
  if (i < B) {
    float tau = *tau_p;
    float w[CC];
    const float2* p = reinterpret_cast<const float2*>(wap + (size_t)i * CC);
#pragma unroll
    for (int c = 0; c < CC / 2; ++c) { float2 t = p[c]; w[2*c] = t.x; w[2*c+1] = t.y; }
    float alpha = -logf(beta[i] / tau);
    float q[CC];
    if (alpha > 1.0f) {
      float s = 0.f;
#pragma unroll
      for (int c = 0; c < CC; ++c) { q[c] = powf(w[c], alpha); s += q[c]; }
#pragma unroll
      for (int c = 0; c < CC; ++c) q[c] = q[c] / s;
    } else {
#pragma unroll
      for (int c = 0; c < CC; ++c) q[c] = w[c];
    }
    float mp = q[0]; int tg = 0;
#pragma unroll
    for (int c = 1; c < CC; ++c) if (q[c] > mp) { mp = q[c]; tg = c; }
    f = (flag0[i] && (mp > 0.1f)) ? 1 : 0;
    float2* qo = reinterpret_cast<float2*>(qbuf + (size_t)i * CC);
#pragma unroll
    for (int c = 0; c < CC / 2; ++c) { float2 t; t.x = q[2*c]; t.y = q[2*c+1]; qo[c] = t; }
    target[i] = tg;
    flag1[i] = f;
    if (f) atomicAdd(&lcnt[tg], 1);   // LDS atomic, contained in block
  }
  __shared__ int red[256];
  red[threadIdx.x] = f;
  __syncthreads();
  for (int off = 128; off; off >>= 1) {
    if (threadIdx.x < off) red[threadIdx.x] += red[threadIdx.x + off];
    __syncthreads();
  }
  if (threadIdx.x == 0) blockcnt[blockIdx.x] = red[0];
  if (threadIdx.x < CC) {
    int v = lcnt[threadIdx.x];
    if (v) atomicAdd(&counts[threadIdx.x], v);   // <=10 global atomics per block
  }
}

// ---------------- K6: self-scan block offsets, weights, outputs, loss parts -
__global__ __launch_bounds__(256)
void k6_out(const int* __restrict__ flag1, const int* __restrict__ target,
            const int* __restrict__ labels, const int* __restrict__ blockcnt,
            const float* __restrict__ a_strong, const float* __restrict__ qbuf,
            const int* __restrict__ counts, float* __restrict__ out,
            float* __restrict__ lossp, int n_host, int nb, int B)
{
  __shared__ int tmp[256];
  __shared__ float wavg_s[CC];
  int t = threadIdx.x;

  // scan all block counts -> this block's offset + total n
  int bv = (t < nb) ? blockcnt[t] : 0;
  tmp[t] = bv;
  __syncthreads();
  for (int off = 1; off < 256; off <<= 1) {
    int u = (t >= off) ? tmp[t - off] : 0;
    __syncthreads();
    tmp[t] += u;
    __syncthreads();
  }
  int n    = tmp[255];
  int boff = (blockIdx.x > 0) ? tmp[blockIdx.x - 1] : 0;
  if (t == 0) {
    float wt[CC]; float sumw = 0.f;
    for (int c = 0; c < CC; ++c) {
      int cnt = counts[c];
      float w_ = (cnt > 0) ? 1.0f / logf(1.02f + (float)cnt / (float)n) : 1.0f;
      wt[c] = w_; sumw += w_;
    }
    float meanw = sumw / (float)CC;
    for (int c = 0; c < CC; ++c) wavg_s[c] = wt[c] / sumw * meanw;
  }
  __syncthreads();

  int i = blockIdx.x * 256 + t;
  int f = (i < B) ? flag1[i] : 0;
  tmp[t] = f;
  __syncthreads();
  for (int off = 1; off < 256; off <<= 1) {
    int u = (t >= off) ? tmp[t - off] : 0;
    __syncthreads();
    tmp[t] += u;
    __syncthreads();
  }
  int pos = boff + tmp[t] - f;
  float part = 0.f;
  if (f) {
    out[1 + pos] = (float)target[i];
    out[1 + n_host + pos] = (float)labels[i];
    float x[CC];
    const float2* p = reinterpret_cast<const float2*>(a_strong + (size_t)i * CC);
#pragma unroll
    for (int c = 0; c < CC / 2; ++c) { float2 u2 = p[c]; x[2*c] = u2.x; x[2*c+1] = u2.y; }
    float m = x[0];
#pragma unroll
    for (int c = 1; c < CC; ++c) m = fmaxf(m, x[c]);
    float s = 0.f;
#pragma unroll
    for (int c = 0; c < CC; ++c) s += expf(x[c] - m);
    float lse = m + logf(s);
    const float2* qp = reinterpret_cast<const float2*>(qbuf + (size_t)i * CC);
    float q[CC];
#pragma unroll
    for (int c = 0; c < CC / 2; ++c) { float2 u2 = qp[c]; q[2*c] = u2.x; q[2*c+1] = u2.y; }
#pragma unroll
    for (int c = 0; c < CC; ++c) part += wavg_s[c] * q[c] * (x[c] - lse);
  }
  __shared__ float red[256];
  red[t] = part;
  __syncthreads();
  for (int off = 128; off; off >>= 1) {
    if (t < off) red[t] += red[t + off];
    __syncthreads();
  }
  if (t == 0) lossp[blockIdx.x] = red[0];
}

// ---------------- K7: finalize ----------------------------------------------
__global__ __launch_bounds__(256)
void k7_fin(const float* __restrict__ lossp, int nb, const int* __restrict__ blockcnt,
            float* __restrict__ out, int n_host)
{
  __shared__ float red[256];
  __shared__ int   redi[256];
  int t = threadIdx.x;
  float s = 0.f; int ns = 0;
  for (int jj = t; jj < nb; jj += 256) { s += lossp[jj]; ns += blockcnt[jj]; }
  red[t] = s; redi[t] = ns;
  __syncthreads();
  for (int off = 128; off; off >>= 1) {
    if (t < off) { red[t] += red[t + off]; redi[t] += redi[t + off]; }
    __syncthreads();
  }
  if (t == 0) {
    int n = redi[0];
    out[0] = -red[0] / (float)n;
    out[1 + 2 * n_host] = (float)n;
  }
}

extern "C" void kernel_launch(void* const* d_in, const int* in_sizes, int n_in,
                              void* d_out, int out_size, void* d_ws, size_t ws_size,
                              hipStream_t stream)
{
  const float* aw     = (const float*)d_in[0];
  const float* astr   = (const float*)d_in[1];
  const float* an     = (const float*)d_in[2];
  const float* nbr    = (const float*)d_in[3];
  const int*   labels = (const int*)d_in[4];
  const float* att    = (const float*)d_in[6];
  const float* proj   = (const float*)d_in[7];
  float* out = (float*)d_out;

  int B = in_sizes[4];
  int C = in_sizes[6];
  int K = (B > 0 && C > 0) ? in_sizes[3] / (B * C) : 0;
  if (C != CC || K != KK) return;
  int n_host = (out_size - 2) / 2;
  int nb = (B + 255) / 256;
  if (nb > 256) return;

  char* w = (char*)d_ws;
  size_t o = 0;
  auto alloc = [&](size_t bytes) { size_t r = o; o += (bytes + 255) & ~(size_t)255; return r; };
  size_t o_wap  = alloc((size_t)B * CC * 4);
  size_t o_q    = alloc((size_t)B * CC * 4);
  size_t o_beta = alloc((size_t)B * 4);
  size_t o_tgt  = alloc((size_t)B * 4);
  size_t o_f0   = alloc((size_t)B * 4);
  size_t o_f1   = alloc((size_t)B * 4);
  size_t o_bc   = alloc((size_t)nb * 4);
  size_t o_lp   = alloc((size_t)nb * 4);
  size_t zstart = o;                       // zeroed-by-memset: h1, cnt, scal
  size_t o_h1   = alloc(65536 * 4);
  size_t o_cnt  = alloc(64);
  size_t o_scal = alloc(64);
  size_t ztotal = o - zstart;
  size_t o_h2   = alloc(65536 * 4);        // zeroed inside k3b_sel
  if (o > ws_size) return;

  float* wap   = (float*)(w + o_wap);
  float* qbuf  = (float*)(w + o_q);
  float* beta  = (float*)(w + o_beta);
  int*   tgt   = (int*)(w + o_tgt);
  int*   f0    = (int*)(w + o_f0);
  int*   f1    = (int*)(w + o_f1);
  int*   bcnt  = (int*)(w + o_bc);
  float* lossp = (float*)(w + o_lp);
  int*   h1    = (int*)(w + o_h1);
  int*   h2    = (int*)(w + o_h2);
  int*   cnts  = (int*)(w + o_cnt);
  int*   scal  = (int*)(w + o_scal);
  float* taup  = (float*)(scal + 8);

  hipMemsetAsync(w + zstart, 0, ztotal, stream);

  int nbA = (B + RPB - 1) / RPB;
  kA      <<<nbA, 256, 0, stream>>>(aw, an, nbr, att, proj, wap, beta, f0, scal, h1, B);
  k3b_sel <<<1, 1024, 0, stream>>>(h1, scal, h2);
  k3c_hist2<<<nb, 256, 0, stream>>>(beta, f0, scal, h2, B);
  k3d_tau <<<1, 1024, 0, stream>>>(h2, scal, taup);
  k4_q    <<<nb, 256, 0, stream>>>(wap, beta, f0, taup, qbuf, tgt, f1,
                                   cnts, bcnt, B);
  k6_out  <<<nb, 256, 0, stream>>>(f1, tgt, labels, bcnt, astr, qbuf, cnts,
                                   out, lossp, n_host, nb, B);
  k7_fin  <<<1, 256, 0, stream>>>(lossp, nb, bcnt, out, n_host);
}

// Round 5
// 142.680 us; speedup vs baseline: 1.8547x; 1.8547x over previous
//
#include <hip/hip_runtime.h>
#include <math.h>

#define CC 10   // classes
#define KK 50   // neighbors

// ---- kA: wave-per-row attention beta + fused wap/flag0/hist ----------------
// lanes 0..49 = neighbors; q_hat reduced via wave-local LDS transpose;
// epilogue (beta, wap) parallel over lanes 0..9.
__global__ __launch_bounds__(256)
void kA(const float* __restrict__ aw, const float* __restrict__ an,
        const float* __restrict__ nbr, const float* __restrict__ att,
        const float* __restrict__ proj,
        float* __restrict__ wap, float* __restrict__ beta,
        int* __restrict__ flag0, int* __restrict__ hist, int B)
{
  __shared__ float xpose[4 * 500];          // per-wave 500-word region (8 KB)

  int tid  = threadIdx.x;
  int wave = tid >> 6;
  int lane = tid & 63;
  int row  = blockIdx.x * 4 + wave;
  bool rv  = (row < B);
  int lrow = rv ? row : 0;                  // clamp for safe loads

  bool l10 = (lane < CC);
  float iv  = (l10 && rv) ? an[(size_t)lrow * CC + lane] : 0.f;
  float awv = (l10 && rv) ? aw[(size_t)lrow * CC + lane] : 0.f;
  float cv  = 0.f;
  if (l10) { float d = proj[lane * CC + lane]; cv = att[lane] * d * d; }

  // broadcast anchors row + coef to all lanes
  float img[CC], ci[CC];
#pragma unroll
  for (int c = 0; c < CC; ++c) {
    img[c] = __shfl(iv, c);
    ci[c]  = __shfl(cv, c) * img[c];
  }

  bool act = (lane < KK);
  float nb[CC];
  if (act && rv) {
    const float2* p = reinterpret_cast<const float2*>(nbr + ((size_t)lrow * KK + lane) * CC);
#pragma unroll
    for (int c = 0; c < CC / 2; ++c) { float2 t = p[c]; nb[2*c] = t.x; nb[2*c+1] = t.y; }
  } else {
#pragma unroll
    for (int c = 0; c < CC; ++c) nb[c] = 0.f;
  }

  // att score + leaky_relu (no max-subtraction: inputs are O(1), exp-safe)
  float s = 0.f;
#pragma unroll
  for (int c = 0; c < CC; ++c) s = fmaf(ci[c], nb[c], s);
  s = (s > 0.f) ? s : 0.01f * s;

  float en[CC]; float sn = 0.f;
#pragma unroll
  for (int c = 0; c < CC; ++c) { en[c] = expf(nb[c]); sn += en[c]; }

  float e = act ? expf(s) : 0.f;
  float den = e;
#pragma unroll
  for (int off = 1; off <= 32; off <<= 1) den += __shfl_xor(den, off);

  // v[c] = (e/sn) * en[c]; write c-major to this wave's LDS region
  float u = e * __builtin_amdgcn_rcpf(sn);
  if (act) {
    float* wbase = &xpose[wave * 500 + lane];
#pragma unroll
    for (int c = 0; c < CC; ++c) wbase[c * 50] = en[c] * u;
  }
  __syncthreads();

  // owner lanes: comp c = lane&15 (<10), k-chunk by g = lane>>4
  int g = lane >> 4;
  int c = lane & 15;
  int cfix = (c < CC) ? c : 0;
  int ks   = (g == 0) ? 0 : (g == 1) ? 13 : (g == 2) ? 26 : 38;
  int cnt  = (g < 2) ? 13 : 12;
  const float* bp = &xpose[wave * 500 + cfix * 50 + ks];
  float P = 0.f;
#pragma unroll
  for (int r = 0; r < 13; ++r) if (r < cnt) P += bp[r];
  P += __shfl_xor(P, 16);
  P += __shfl_xor(P, 32);                   // all lanes with comp c have full sum

  float invd = __builtin_amdgcn_rcpf(den);

  // beta = || softmax(anchors) - q_hat ||^2, parallel over lanes 0..9
  float apx = l10 ? expf(iv) : 0.f;
  float s2 = apx;
#pragma unroll
  for (int off = 1; off <= 8; off <<= 1) s2 += __shfl_xor(s2, off);
  float d1 = apx * __builtin_amdgcn_rcpf(s2) - P * invd;
  float dd = l10 ? d1 * d1 : 0.f;
#pragma unroll
  for (int off = 1; off <= 8; off <<= 1) dd += __shfl_xor(dd, off);

  // wap = softmax(anchors_weak), parallel over lanes 0..9
  float exw = l10 ? expf(awv) : 0.f;
  float sw = exw, mxw = exw;
#pragma unroll
  for (int off = 1; off <= 8; off <<= 1) {
    sw  += __shfl_xor(sw, off);
    mxw  = fmaxf(mxw, __shfl_xor(mxw, off));
  }
  float rsw = __builtin_amdgcn_rcpf(sw);
  if (l10 && rv) wap[(size_t)lrow * CC + lane] = exw * rsw;

  if (lane == 0 && rv) {
    beta[row] = dd;
    float mp = mxw * rsw;
    int f = (mp > 0.15f) ? 1 : 0;
    flag0[row] = f;
    if (f) atomicAdd(&hist[__float_as_uint(dd) >> 16], 1);  // beta>=0: order-preserving
  }
}

// ---------------- K3: exact radix select of k-th smallest beta --------------
// scal: [2]=sel_hi [3]=k2 [4]=k ; (float at [8]) = tau
__global__ __launch_bounds__(1024)
void k3b_sel(const int* __restrict__ hist, int* __restrict__ scal,
             int* __restrict__ hist2_zero)
{
  __shared__ int tmp[1024];
  int t = threadIdx.x;
  for (int jj = 0; jj < 64; ++jj) hist2_zero[t * 64 + jj] = 0;  // zero next pass
  int base = t * 64;
  int sum = 0;
  for (int jj = 0; jj < 64; ++jj) sum += hist[base + jj];
  tmp[t] = sum;
  __syncthreads();
  for (int off = 1; off < 1024; off <<= 1) {
    int v = (t >= off) ? tmp[t - off] : 0;
    __syncthreads();
    tmp[t] += v;
    __syncthreads();
  }
  int cumb = tmp[t] - sum;
  int b = tmp[1023];                 // total flagged count == b_count
  int k = (int)(0.5 * (double)b);    // int(ETA*b)
  if (k < 1) k = 1;
  if (t == 0) scal[4] = k;
  if (b > 0 && k > cumb && k <= cumb + sum) {
    int c = cumb;
    for (int jj = 0; jj < 64; ++jj) {
      int h = hist[base + jj];
      if (k <= c + h) { scal[2] = base + jj; scal[3] = k - c; break; }
      c += h;
    }
  }
  if (b == 0 && t == 0) { scal[2] = 0; scal[3] = 1; }
}

__global__ __launch_bounds__(256)
void k3c_hist2(const float* __restrict__ beta, const int* __restrict__ flag0,
               const int* __restrict__ scal, int* __restrict__ hist2, int B)
{
  int i = blockIdx.x * 256 + threadIdx.x;
  if (i >= B) return;
  if (flag0[i]) {
    unsigned key = __float_as_uint(beta[i]);
    if ((int)(key >> 16) == scal[2]) atomicAdd(&hist2[key & 0xFFFF], 1);
  }
}

__global__ __launch_bounds__(1024)
void k3d_tau(const int* __restrict__ hist2, int* __restrict__ scal,
             float* __restrict__ tau)
{
  __shared__ int tmp[1024];
  int t = threadIdx.x;
  int base = t * 64;
  int sum = 0;
  for (int jj = 0; jj < 64; ++jj) sum += hist2[base + jj];
  tmp[t] = sum;
  __syncthreads();
  for (int off = 1; off < 1024; off <<= 1) {
    int v = (t >= off) ? tmp[t - off] : 0;
    __syncthreads();
    tmp[t] += v;
    __syncthreads();
  }
  int cumb = tmp[t] - sum;
  int k2 = scal[3];
  if (k2 > cumb && k2 <= cumb + sum) {
    int c = cumb;
    for (int jj = 0; jj < 64; ++jj) {
      int h = hist2[base + jj];
      if (k2 <= c + h) {
        unsigned key = (((unsigned)scal[2]) << 16) | (unsigned)(base + jj);
        float bk = __uint_as_float(key);
        *tau = bk / expf(-1.0f);
        break;
      }
      c += h;
    }
  }
}

// ---------------- K4: q, target, mask1, per-block counts --------------------
__global__ __launch_bounds__(256)
void k4_q(const float* __restrict__ wap, const float* __restrict__ beta,
          const int* __restrict__ flag0, const float* __restrict__ tau_p,
          float* __restrict__ qbuf, int* __restrict__ target, int* __restrict__ flag1,
          int* __restrict__ counts, int* __restrict__ blockcnt, int B)
{
  __shared__ int lcnt[CC];
  if (threadIdx.x < CC) lcnt[threadIdx.x] = 0;
  __syncthreads();

  int i = blockIdx.x * 256 + threadIdx.x;
  int f = 0;
  if (i < B) {
    float tau = *tau_p;
    float w[CC];
    const float2* p = reinterpret_cast<const float2*>(wap + (size_t)i * CC);
#pragma unroll
    for (int c = 0; c < CC / 2; ++c) { float2 t = p[c]; w[2*c] = t.x; w[2*c+1] = t.y; }
    float alpha = -logf(beta[i] / tau);
    float q[CC];
    if (alpha > 1.0f) {
      float s = 0.f;
#pragma unroll
      for (int c = 0; c < CC; ++c) { q[c] = exp2f(alpha * log2f(w[c])); s += q[c]; }
#pragma unroll
      for (int c = 0; c < CC; ++c) q[c] = q[c] / s;
    } else {
#pragma unroll
      for (int c = 0; c < CC; ++c) q[c] = w[c];
    }
    float mp = q[0]; int tg = 0;
#pragma unroll
    for (int c = 1; c < CC; ++c) if (q[c] > mp) { mp = q[c]; tg = c; }
    f = (flag0[i] && (mp > 0.1f)) ? 1 : 0;
    float2* qo = reinterpret_cast<float2*>(qbuf + (size_t)i * CC);
#pragma unroll
    for (int c = 0; c < CC / 2; ++c) { float2 t; t.x = q[2*c]; t.y = q[2*c+1]; qo[c] = t; }
    target[i] = tg;
    flag1[i] = f;
    if (f) atomicAdd(&lcnt[tg], 1);   // LDS atomic, contained in block
  }
  __shared__ int red[256];
  red[threadIdx.x] = f;
  __syncthreads();
  for (int off = 128; off; off >>= 1) {
    if (threadIdx.x < off) red[threadIdx.x] += red[threadIdx.x + off];
    __syncthreads();
  }
  if (threadIdx.x == 0) blockcnt[blockIdx.x] = red[0];
  if (threadIdx.x < CC) {
    int v = lcnt[threadIdx.x];
    if (v) atomicAdd(&counts[threadIdx.x], v);   // <=10 global atomics per block
  }
}

// ---------------- K6: self-scan block offsets, weights, outputs, loss parts -
__global__ __launch_bounds__(256)
void k6_out(const int* __restrict__ flag1, const int* __restrict__ target,
            const int* __restrict__ labels, const int* __restrict__ blockcnt,
            const float* __restrict__ a_strong, const float* __restrict__ qbuf,
            const int* __restrict__ counts, float* __restrict__ out,
            float* __restrict__ lossp, int n_host, int nb, int B)
{
  __shared__ int tmp[256];
  __shared__ float wavg_s[CC];
  int t = threadIdx.x;

  int bv = (t < nb) ? blockcnt[t] : 0;
  tmp[t] = bv;
  __syncthreads();
  for (int off = 1; off < 256; off <<= 1) {
    int u = (t >= off) ? tmp[t - off] : 0;
    __syncthreads();
    tmp[t] += u;
    __syncthreads();
  }
  int n    = tmp[255];
  int boff = (blockIdx.x > 0) ? tmp[blockIdx.x - 1] : 0;
  if (t == 0) {
    float wt[CC]; float sumw = 0.f;
    for (int c = 0; c < CC; ++c) {
      int cnt = counts[c];
      float w_ = (cnt > 0) ? 1.0f / logf(1.02f + (float)cnt / (float)n) : 1.0f;
      wt[c] = w_; sumw += w_;
    }
    float meanw = sumw / (float)CC;
    for (int c = 0; c < CC; ++c) wavg_s[c] = wt[c] / sumw * meanw;
  }
  __syncthreads();

  int i = blockIdx.x * 256 + t;
  int f = (i < B) ? flag1[i] : 0;
  tmp[t] = f;
  __syncthreads();
  for (int off = 1; off < 256; off <<= 1) {
    int u = (t >= off) ? tmp[t - off] : 0;
    __syncthreads();
    tmp[t] += u;
    __syncthreads();
  }
  int pos = boff + tmp[t] - f;
  float part = 0.f;
  if (f) {
    out[1 + pos] = (float)target[i];
    out[1 + n_host + pos] = (float)labels[i];
    float x[CC];
    const float2* p = reinterpret_cast<const float2*>(a_strong + (size_t)i * CC);
#pragma unroll
    for (int c = 0; c < CC / 2; ++c) { float2 u2 = p[c]; x[2*c] = u2.x; x[2*c+1] = u2.y; }
    float m = x[0];
#pragma unroll
    for (int c = 1; c < CC; ++c) m = fmaxf(m, x[c]);
    float s = 0.f;
#pragma unroll
    for (int c = 0; c < CC; ++c) s += expf(x[c] - m);
    float lse = m + logf(s);
    const float2* qp = reinterpret_cast<const float2*>(qbuf + (size_t)i * CC);
    float q[CC];
#pragma unroll
    for (int c = 0; c < CC / 2; ++c) { float2 u2 = qp[c]; q[2*c] = u2.x; q[2*c+1] = u2.y; }
#pragma unroll
    for (int c = 0; c < CC; ++c) part += wavg_s[c] * q[c] * (x[c] - lse);
  }
  __shared__ float red[256];
  red[t] = part;
  __syncthreads();
  for (int off = 128; off; off >>= 1) {
    if (t < off) red[t] += red[t + off];
    __syncthreads();
  }
  if (t == 0) lossp[blockIdx.x] = red[0];
}

// ---------------- K7: finalize ----------------------------------------------
__global__ __launch_bounds__(256)
void k7_fin(const float* __restrict__ lossp, int nb, const int* __restrict__ blockcnt,
            float* __restrict__ out, int n_host)
{
  __shared__ float red[256];
  __shared__ int   redi[256];
  int t = threadIdx.x;
  float s = 0.f; int ns = 0;
  for (int jj = t; jj < nb; jj += 256) { s += lossp[jj]; ns += blockcnt[jj]; }
  red[t] = s; redi[t] = ns;
  __syncthreads();
  for (int off = 128; off; off >>= 1) {
    if (t < off) { red[t] += red[t + off]; redi[t] += redi[t + off]; }
    __syncthreads();
  }
  if (t == 0) {
    int n = redi[0];
    out[0] = -red[0] / (float)n;
    out[1 + 2 * n_host] = (float)n;
  }
}

extern "C" void kernel_launch(void* const* d_in, const int* in_sizes, int n_in,
                              void* d_out, int out_size, void* d_ws, size_t ws_size,
                              hipStream_t stream)
{
  const float* aw     = (const float*)d_in[0];
  const float* astr   = (const float*)d_in[1];
  const float* an     = (const float*)d_in[2];
  const float* nbr    = (const float*)d_in[3];
  const int*   labels = (const int*)d_in[4];
  const float* att    = (const float*)d_in[6];
  const float* proj   = (const float*)d_in[7];
  float* out = (float*)d_out;

  int B = in_sizes[4];
  int C = in_sizes[6];
  int K = (B > 0 && C > 0) ? in_sizes[3] / (B * C) : 0;
  if (C != CC || K != KK) return;
  int n_host = (out_size - 2) / 2;
  int nb = (B + 255) / 256;
  if (nb > 256) return;

  char* w = (char*)d_ws;
  size_t o = 0;
  auto alloc = [&](size_t bytes) { size_t r = o; o += (bytes + 255) & ~(size_t)255; return r; };
  size_t o_wap  = alloc((size_t)B * CC * 4);
  size_t o_q    = alloc((size_t)B * CC * 4);
  size_t o_beta = alloc((size_t)B * 4);
  size_t o_tgt  = alloc((size_t)B * 4);
  size_t o_f0   = alloc((size_t)B * 4);
  size_t o_f1   = alloc((size_t)B * 4);
  size_t o_bc   = alloc((size_t)nb * 4);
  size_t o_lp   = alloc((size_t)nb * 4);
  size_t zstart = o;                       // zeroed-by-memset: h1, cnt, scal
  size_t o_h1   = alloc(65536 * 4);
  size_t o_cnt  = alloc(64);
  size_t o_scal = alloc(64);
  size_t ztotal = o - zstart;
  size_t o_h2   = alloc(65536 * 4);        // zeroed inside k3b_sel
  if (o > ws_size) return;

  float* wap   = (float*)(w + o_wap);
  float* qbuf  = (float*)(w + o_q);
  float* beta  = (float*)(w + o_beta);
  int*   tgt   = (int*)(w + o_tgt);
  int*   f0    = (int*)(w + o_f0);
  int*   f1    = (int*)(w + o_f1);
  int*   bcnt  = (int*)(w + o_bc);
  float* lossp = (float*)(w + o_lp);
  int*   h1    = (int*)(w + o_h1);
  int*   h2    = (int*)(w + o_h2);
  int*   cnts  = (int*)(w + o_cnt);
  int*   scal  = (int*)(w + o_scal);
  float* taup  = (float*)(scal + 8);

  hipMemsetAsync(w + zstart, 0, ztotal, stream);

  int nbA = (B + 3) / 4;
  kA      <<<nbA, 256, 0, stream>>>(aw, an, nbr, att, proj, wap, beta, f0, h1, B);
  k3b_sel <<<1, 1024, 0, stream>>>(h1, scal, h2);
  k3c_hist2<<<nb, 256, 0, stream>>>(beta, f0, scal, h2, B);
  k3d_tau <<<1, 1024, 0, stream>>>(h2, scal, taup);
  k4_q    <<<nb, 256, 0, stream>>>(wap, beta, f0, taup, qbuf, tgt, f1,
                                   cnts, bcnt, B);
  k6_out  <<<nb, 256, 0, stream>>>(f1, tgt, labels, bcnt, astr, qbuf, cnts,
                                   out, lossp, n_host, nb, B);
  k7_fin  <<<1, 256, 0, stream>>>(lossp, nb, bcnt, out, n_host);
}

// Round 6
// 134.618 us; speedup vs baseline: 1.9658x; 1.0599x over previous
//
#include <hip/hip_runtime.h>
#include <math.h>

#define CC 10   // classes
#define KK 50   // neighbors

// ---- kA: wave-per-row attention beta + fused wap/flag0/hist ----------------
// Stage: each wave copies its row (500 floats) to LDS via 2 coalesced float4
// loads per lane.  Compute: lanes 0..49 = neighbors, reading 40B segments
// from LDS.  q_hat reduced via wave-local LDS transpose; epilogue parallel
// over lanes 0..9.
__global__ __launch_bounds__(256)
void kA(const float* __restrict__ aw, const float* __restrict__ an,
        const float* __restrict__ nbr, const float* __restrict__ att,
        const float* __restrict__ proj,
        float* __restrict__ wap, float* __restrict__ beta,
        int* __restrict__ flag0, int* __restrict__ hist, int B)
{
  __shared__ float sb[4 * 512];             // staged rows (float4-aligned)
  __shared__ float xp[4 * 500];             // transposed v for q_hat reduce

  int tid  = threadIdx.x;
  int wave = tid >> 6;
  int lane = tid & 63;
  int row  = blockIdx.x * 4 + wave;
  bool rv  = (row < B);
  int lrow = rv ? row : 0;                  // clamp for safe loads

  // ---- coalesced stage: 125 float4 per row, 2 loads/lane -------------------
  const float4* src = reinterpret_cast<const float4*>(nbr + (size_t)lrow * (KK * CC));
  float4 v0 = src[lane];
  bool second = (lane < 61);                // 64+lane < 125
  float4 v1 = second ? src[64 + lane] : make_float4(0.f, 0.f, 0.f, 0.f);
  float4* wb4 = reinterpret_cast<float4*>(&sb[wave * 512]);
  wb4[lane] = v0;
  if (second) wb4[64 + lane] = v1;

  bool l10 = (lane < CC);
  float iv  = (l10 && rv) ? an[(size_t)lrow * CC + lane] : 0.f;
  float awv = (l10 && rv) ? aw[(size_t)lrow * CC + lane] : 0.f;
  float cv  = 0.f;
  if (l10) { float d = proj[lane * CC + lane]; cv = att[lane] * d * d; }

  // broadcast anchors row + coef to all lanes
  float img[CC], ci[CC];
#pragma unroll
  for (int c = 0; c < CC; ++c) {
    img[c] = __shfl(iv, c);
    ci[c]  = __shfl(cv, c) * img[c];
  }
  __syncthreads();

  // ---- per-neighbor work from LDS ------------------------------------------
  bool act = (lane < KK);
  int segk = act ? lane : 0;
  const float2* seg2 = reinterpret_cast<const float2*>(&sb[wave * 512 + segk * CC]);
  float nb[CC];
#pragma unroll
  for (int c = 0; c < CC / 2; ++c) { float2 t = seg2[c]; nb[2*c] = t.x; nb[2*c+1] = t.y; }

  // att score + leaky_relu (no max-subtraction: inputs O(1), exp-safe in f32)
  float s = 0.f;
#pragma unroll
  for (int c = 0; c < CC; ++c) s = fmaf(ci[c], nb[c], s);
  s = (s > 0.f) ? s : 0.01f * s;

  float en[CC]; float sn = 0.f;
#pragma unroll
  for (int c = 0; c < CC; ++c) { en[c] = expf(nb[c]); sn += en[c]; }

  float e = act ? expf(s) : 0.f;
  float den = e;
#pragma unroll
  for (int off = 1; off <= 32; off <<= 1) den += __shfl_xor(den, off);

  // v[c] = (e/sn)*en[c]; write c-major (stride 50) for owner-lane reduction
  float u = e * __builtin_amdgcn_rcpf(sn);
  if (act) {
    float* wbase = &xp[wave * 500 + lane];
#pragma unroll
    for (int c = 0; c < CC; ++c) wbase[c * 50] = en[c] * u;
  }
  __syncthreads();

  // owner lanes: comp c = lane&15 (<10), k-chunk by g = lane>>4
  int g = lane >> 4;
  int c = lane & 15;
  int cfix = (c < CC) ? c : 0;
  int ks   = (g == 0) ? 0 : (g == 1) ? 13 : (g == 2) ? 26 : 38;
  int cnt  = (g < 2) ? 13 : 12;
  const float* bp = &xp[wave * 500 + cfix * 50 + ks];
  float P = 0.f;
#pragma unroll
  for (int r = 0; r < 13; ++r) if (r < cnt) P += bp[r];
  P += __shfl_xor(P, 16);
  P += __shfl_xor(P, 32);                   // all lanes with comp c have full sum

  float invd = __builtin_amdgcn_rcpf(den);

  // beta = || softmax(anchors) - q_hat ||^2, parallel over lanes 0..9
  float apx = l10 ? expf(iv) : 0.f;
  float s2 = apx;
#pragma unroll
  for (int off = 1; off <= 8; off <<= 1) s2 += __shfl_xor(s2, off);
  float d1 = apx * __builtin_amdgcn_rcpf(s2) - P * invd;
  float dd = l10 ? d1 * d1 : 0.f;
#pragma unroll
  for (int off = 1; off <= 8; off <<= 1) dd += __shfl_xor(dd, off);

  // wap = softmax(anchors_weak), parallel over lanes 0..9
  float exw = l10 ? expf(awv) : 0.f;
  float sw = exw, mxw = exw;
#pragma unroll
  for (int off = 1; off <= 8; off <<= 1) {
    sw  += __shfl_xor(sw, off);
    mxw  = fmaxf(mxw, __shfl_xor(mxw, off));
  }
  float rsw = __builtin_amdgcn_rcpf(sw);
  if (l10 && rv) wap[(size_t)lrow * CC + lane] = exw * rsw;

  if (lane == 0 && rv) {
    beta[row] = dd;
    float mp = mxw * rsw;
    int f = (mp > 0.15f) ? 1 : 0;
    flag0[row] = f;
    if (f) atomicAdd(&hist[__float_as_uint(dd) >> 16], 1);  // beta>=0: order-preserving
  }
}

// ---------------- K3: exact radix select of k-th smallest beta --------------
// scal: [2]=sel_hi [3]=k2 [4]=k ; (float at [8]) = tau
__global__ __launch_bounds__(1024)
void k3b_sel(const int* __restrict__ hist, int* __restrict__ scal)
{
  __shared__ int tmp[1024];
  int t = threadIdx.x;
  int base = t * 64;
  const int4* h4 = reinterpret_cast<const int4*>(hist + base);
  int sum = 0;
#pragma unroll
  for (int jj = 0; jj < 16; ++jj) { int4 v = h4[jj]; sum += v.x + v.y + v.z + v.w; }
  tmp[t] = sum;
  __syncthreads();
  for (int off = 1; off < 1024; off <<= 1) {
    int v = (t >= off) ? tmp[t - off] : 0;
    __syncthreads();
    tmp[t] += v;
    __syncthreads();
  }
  int cumb = tmp[t] - sum;
  int b = tmp[1023];                 // total flagged count == b_count
  int k = (int)(0.5 * (double)b);    // int(ETA*b)
  if (k < 1) k = 1;
  if (t == 0) scal[4] = k;
  if (b > 0 && k > cumb && k <= cumb + sum) {
    int c = cumb;
    for (int jj = 0; jj < 64; ++jj) {
      int h = hist[base + jj];
      if (k <= c + h) { scal[2] = base + jj; scal[3] = k - c; break; }
      c += h;
    }
  }
  if (b == 0 && t == 0) { scal[2] = 0; scal[3] = 1; }
}

__global__ __launch_bounds__(256)
void k3c_hist2(const float* __restrict__ beta, const int* __restrict__ flag0,
               const int* __restrict__ scal, int* __restrict__ hist2, int B)
{
  int i = blockIdx.x * 256 + threadIdx.x;
  if (i >= B) return;
  if (flag0[i]) {
    unsigned key = __float_as_uint(beta[i]);
    if ((int)(key >> 16) == scal[2]) atomicAdd(&hist2[key & 0xFFFF], 1);
  }
}

__global__ __launch_bounds__(1024)
void k3d_tau(const int* __restrict__ hist2, int* __restrict__ scal,
             float* __restrict__ tau)
{
  __shared__ int tmp[1024];
  int t = threadIdx.x;
  int base = t * 64;
  const int4* h4 = reinterpret_cast<const int4*>(hist2 + base);
  int sum = 0;
#pragma unroll
  for (int jj = 0; jj < 16; ++jj) { int4 v = h4[jj]; sum += v.x + v.y + v.z + v.w; }
  tmp[t] = sum;
  __syncthreads();
  for (int off = 1; off < 1024; off <<= 1) {
    int v = (t >= off) ? tmp[t - off] : 0;
    __syncthreads();
    tmp[t] += v;
    __syncthreads();
  }
  int cumb = tmp[t] - sum;
  int k2 = scal[3];
  if (k2 > cumb && k2 <= cumb + sum) {
    int c = cumb;
    for (int jj = 0; jj < 64; ++jj) {
      int h = hist2[base + jj];
      if (k2 <= c + h) {
        unsigned key = (((unsigned)scal[2]) << 16) | (unsigned)(base + jj);
        float bk = __uint_as_float(key);
        *tau = bk / expf(-1.0f);
        break;
      }
      c += h;
    }
  }
}

// ---------------- K4: q, target, mask1, per-block counts --------------------
__global__ __launch_bounds__(256)
void k4_q(const float* __restrict__ wap, const float* __restrict__ beta,
          const int* __restrict__ flag0, const float* __restrict__ tau_p,
          float* __restrict__ qbuf, int* __restrict__ target, int* __restrict__ flag1,
          int* __restrict__ counts, int* __restrict__ blockcnt, int B)
{
  __shared__ int lcnt[CC];
  if (threadIdx.x < CC) lcnt[threadIdx.x] = 0;
  __syncthreads();

  int i = blockIdx.x * 256 + threadIdx.x;
  int f = 0;
  if (i < B) {
    float tau = *tau_p;
    float w[CC];
    const float2* p = reinterpret_cast<const float2*>(wap + (size_t)i * CC);
#pragma unroll
    for (int c = 0; c < CC / 2; ++c) { float2 t = p[c]; w[2*c] = t.x; w[2*c+1] = t.y; }
    float alpha = -logf(beta[i] / tau);
    float q[CC];
    if (alpha > 1.0f) {
      float s = 0.f;
#pragma unroll
      for (int c = 0; c < CC; ++c) { q[c] = exp2f(alpha * log2f(w[c])); s += q[c]; }
#pragma unroll
      for (int c = 0; c < CC; ++c) q[c] = q[c] / s;
    } else {
#pragma unroll
      for (int c = 0; c < CC; ++c) q[c] = w[c];
    }
    float mp = q[0]; int tg = 0;
#pragma unroll
    for (int c = 1; c < CC; ++c) if (q[c] > mp) { mp = q[c]; tg = c; }
    f = (flag0[i] && (mp > 0.1f)) ? 1 : 0;
    float2* qo = reinterpret_cast<float2*>(qbuf + (size_t)i * CC);
#pragma unroll
    for (int c = 0; c < CC / 2; ++c) { float2 t; t.x = q[2*c]; t.y = q[2*c+1]; qo[c] = t; }
    target[i] = tg;
    flag1[i] = f;
    if (f) atomicAdd(&lcnt[tg], 1);   // LDS atomic, contained in block
  }
  __shared__ int red[256];
  red[threadIdx.x] = f;
  __syncthreads();
  for (int off = 128; off; off >>= 1) {
    if (threadIdx.x < off) red[threadIdx.x] += red[threadIdx.x + off];
    __syncthreads();
  }
  if (threadIdx.x == 0) blockcnt[blockIdx.x] = red[0];
  if (threadIdx.x < CC) {
    int v = lcnt[threadIdx.x];
    if (v) atomicAdd(&counts[threadIdx.x], v);   // <=10 global atomics per block
  }
}

// ---------------- K6: self-scan block offsets, weights, outputs, loss parts -
__global__ __launch_bounds__(256)
void k6_out(const int* __restrict__ flag1, const int* __restrict__ target,
            const int* __restrict__ labels, const int* __restrict__ blockcnt,
            const float* __restrict__ a_strong, const float* __restrict__ qbuf,
            const int* __restrict__ counts, float* __restrict__ out,
            float* __restrict__ lossp, int n_host, int nb, int B)
{
  __shared__ int tmp[256];
  __shared__ float wavg_s[CC];
  int t = threadIdx.x;

  int bv = (t < nb) ? blockcnt[t] : 0;
  tmp[t] = bv;
  __syncthreads();
  for (int off = 1; off < 256; off <<= 1) {
    int u = (t >= off) ? tmp[t - off] : 0;
    __syncthreads();
    tmp[t] += u;
    __syncthreads();
  }
  int n    = tmp[255];
  int boff = (blockIdx.x > 0) ? tmp[blockIdx.x - 1] : 0;
  if (t == 0) {
    float wt[CC]; float sumw = 0.f;
    for (int c = 0; c < CC; ++c) {
      int cnt = counts[c];
      float w_ = (cnt > 0) ? 1.0f / logf(1.02f + (float)cnt / (float)n) : 1.0f;
      wt[c] = w_; sumw += w_;
    }
    float meanw = sumw / (float)CC;
    for (int c = 0; c < CC; ++c) wavg_s[c] = wt[c] / sumw * meanw;
  }
  __syncthreads();

  int i = blockIdx.x * 256 + t;
  int f = (i < B) ? flag1[i] : 0;
  tmp[t] = f;
  __syncthreads();
  for (int off = 1; off < 256; off <<= 1) {
    int u = (t >= off) ? tmp[t - off] : 0;
    __syncthreads();
    tmp[t] += u;
    __syncthreads();
  }
  int pos = boff + tmp[t] - f;
  float part = 0.f;
  if (f) {
    out[1 + pos] = (float)target[i];
    out[1 + n_host + pos] = (float)labels[i];
    float x[CC];
    const float2* p = reinterpret_cast<const float2*>(a_strong + (size_t)i * CC);
#pragma unroll
    for (int c = 0; c < CC / 2; ++c) { float2 u2 = p[c]; x[2*c] = u2.x; x[2*c+1] = u2.y; }
    float m = x[0];
#pragma unroll
    for (int c = 1; c < CC; ++c) m = fmaxf(m, x[c]);
    float s = 0.f;
#pragma unroll
    for (int c = 0; c < CC; ++c) s += expf(x[c] - m);
    float lse = m + logf(s);
    const float2* qp = reinterpret_cast<const float2*>(qbuf + (size_t)i * CC);
    float q[CC];
#pragma unroll
    for (int c = 0; c < CC / 2; ++c) { float2 u2 = qp[c]; q[2*c] = u2.x; q[2*c+1] = u2.y; }
#pragma unroll
    for (int c = 0; c < CC; ++c) part += wavg_s[c] * q[c] * (x[c] - lse);
  }
  __shared__ float red[256];
  red[t] = part;
  __syncthreads();
  for (int off = 128; off; off >>= 1) {
    if (t < off) red[t] += red[t + off];
    __syncthreads();
  }
  if (t == 0) lossp[blockIdx.x] = red[0];
}

// ---------------- K7: finalize ----------------------------------------------
__global__ __launch_bounds__(256)
void k7_fin(const float* __restrict__ lossp, int nb, const int* __restrict__ blockcnt,
            float* __restrict__ out, int n_host)
{
  __shared__ float red[256];
  __shared__ int   redi[256];
  int t = threadIdx.x;
  float s = 0.f; int ns = 0;
  for (int jj = t; jj < nb; jj += 256) { s += lossp[jj]; ns += blockcnt[jj]; }
  red[t] = s; redi[t] = ns;
  __syncthreads();
  for (int off = 128; off; off >>= 1) {
    if (t < off) { red[t] += red[t + off]; redi[t] += redi[t + off]; }
    __syncthreads();
  }
  if (t == 0) {
    int n = redi[0];
    out[0] = -red[0] / (float)n;
    out[1 + 2 * n_host] = (float)n;
  }
}

extern "C" void kernel_launch(void* const* d_in, const int* in_sizes, int n_in,
                              void* d_out, int out_size, void* d_ws, size_t ws_size,
                              hipStream_t stream)
{
  const float* aw     = (const float*)d_in[0];
  const float* astr   = (const float*)d_in[1];
  const float* an     = (const float*)d_in[2];
  const float* nbr    = (const float*)d_in[3];
  const int*   labels = (const int*)d_in[4];
  const float* att    = (const float*)d_in[6];
  const float* proj   = (const float*)d_in[7];
  float* out = (float*)d_out;

  int B = in_sizes[4];
  int C = in_sizes[6];
  int K = (B > 0 && C > 0) ? in_sizes[3] / (B * C) : 0;
  if (C != CC || K != KK) return;
  int n_host = (out_size - 2) / 2;
  int nb = (B + 255) / 256;
  if (nb > 256) return;

  char* w = (char*)d_ws;
  size_t o = 0;
  auto alloc = [&](size_t bytes) { size_t r = o; o += (bytes + 255) & ~(size_t)255; return r; };
  size_t o_wap  = alloc((size_t)B * CC * 4);
  size_t o_q    = alloc((size_t)B * CC * 4);
  size_t o_beta = alloc((size_t)B * 4);
  size_t o_tgt  = alloc((size_t)B * 4);
  size_t o_f0   = alloc((size_t)B * 4);
  size_t o_f1   = alloc((size_t)B * 4);
  size_t o_bc   = alloc((size_t)nb * 4);
  size_t o_lp   = alloc((size_t)nb * 4);
  size_t zstart = o;                       // zeroed-by-memset: h1, h2, cnt, scal
  size_t o_h1   = alloc(65536 * 4);
  size_t o_h2   = alloc(65536 * 4);
  size_t o_cnt  = alloc(64);
  size_t o_scal = alloc(64);
  size_t ztotal = o - zstart;
  if (o > ws_size) return;

  float* wap   = (float*)(w + o_wap);
  float* qbuf  = (float*)(w + o_q);
  float* beta  = (float*)(w + o_beta);
  int*   tgt   = (int*)(w + o_tgt);
  int*   f0    = (int*)(w + o_f0);
  int*   f1    = (int*)(w + o_f1);
  int*   bcnt  = (int*)(w + o_bc);
  float* lossp = (float*)(w + o_lp);
  int*   h1    = (int*)(w + o_h1);
  int*   h2    = (int*)(w + o_h2);
  int*   cnts  = (int*)(w + o_cnt);
  int*   scal  = (int*)(w + o_scal);
  float* taup  = (float*)(scal + 8);

  hipMemsetAsync(w + zstart, 0, ztotal, stream);

  int nbA = (B + 3) / 4;
  kA      <<<nbA, 256, 0, stream>>>(aw, an, nbr, att, proj, wap, beta, f0, h1, B);
  k3b_sel <<<1, 1024, 0, stream>>>(h1, scal);
  k3c_hist2<<<nb, 256, 0, stream>>>(beta, f0, scal, h2, B);
  k3d_tau <<<1, 1024, 0, stream>>>(h2, scal, taup);
  k4_q    <<<nb, 256, 0, stream>>>(wap, beta, f0, taup, qbuf, tgt, f1,
                                   cnts, bcnt, B);
  k6_out  <<<nb, 256, 0, stream>>>(f1, tgt, labels, bcnt, astr, qbuf, cnts,
                                   out, lossp, n_host, nb, B);
  k7_fin  <<<1, 256, 0, stream>>>(lossp, nb, bcnt, out, n_host);
}